// Round 14
// baseline (200.193 us; speedup 1.0000x reference)
//
#include <hip/hip_runtime.h>
#include <hip/hip_bf16.h>

#define FIN 256
#define FH 128
#define FZ 32

typedef unsigned short u16;
typedef unsigned int u32;
typedef __attribute__((ext_vector_type(4))) float f32x4;
typedef __attribute__((ext_vector_type(2))) float f32x2;
typedef __attribute__((ext_vector_type(8))) _Float16 f16x8;
typedef __attribute__((ext_vector_type(4))) _Float16 f16x4;
typedef __attribute__((ext_vector_type(4))) unsigned int uint4v;

__device__ inline u16 f2h(float v) { return __builtin_bit_cast(u16, (_Float16)v); }

// ---------------- prep: zero deg/total + weight convert to fp16 Wt[N][K] ----------------
__global__ __launch_bounds__(256) void prep(const float* __restrict__ W1,
                                            const float* __restrict__ W2,
                                            const float* __restrict__ W3,
                                            u16* __restrict__ w1h, u16* __restrict__ w2h,
                                            u16* __restrict__ w3h, int* __restrict__ deg,
                                            int* __restrict__ total) {
    int b = blockIdx.x, t = threadIdx.x;
    if (b < 256) {
        deg[b * 256 + t] = 0;
        if (b == 0 && t == 0) *total = 0;
        return;
    }
    int i = (b - 256) * 256 + t;
    if (i < FIN * FH) {
        int k = i / FH, n = i % FH;
        w1h[n * FIN + k] = f2h(W1[i]);
    } else if (i < FIN * FH + FH * FH) {
        int j = i - FIN * FH;
        int k = j / FH, n = j % FH;
        w2h[n * FH + k] = f2h(W2[j]);
    } else {
        int j = i - (FIN * FH + FH * FH);
        int k = j / FZ, n = j % FZ;
        w3h[n * FH + k] = f2h(W3[j]);
    }
}

// ---------------- degree count + per-edge rank (atomic return value) ----------------
__global__ void deg_count(const int* __restrict__ dst, int* __restrict__ deg,
                          int* __restrict__ erank, int E) {
    int e = blockIdx.x * 256 + threadIdx.x;
    if (e < E) erank[e] = atomicAdd(&deg[dst[e]], 1);
}

// ---------------- single-kernel scan: block-local scan + atomic base ----------------
__global__ __launch_bounds__(256) void scan_fused(const int* __restrict__ deg,
                                                  int* __restrict__ total,
                                                  int* __restrict__ rowstart,
                                                  float* __restrict__ dis) {
    __shared__ int s[256];
    __shared__ int base;
    int t = threadIdx.x;
    int i = blockIdx.x * 256 + t;
    int v = deg[i];
    s[t] = v;
    __syncthreads();
    for (int o = 1; o < 256; o <<= 1) {
        int add = (t >= o) ? s[t - o] : 0;
        __syncthreads();
        s[t] += add;
        __syncthreads();
    }
    if (t == 255) base = atomicAdd(total, s[255]);
    __syncthreads();
    rowstart[i] = s[t] - v + base;
    dis[i] = rsqrtf((float)v + 1.0f);
}

// ---------------- ln_stats: wave-per-row coalesced stats pass, writes (mu, rsig) only ----------------
__global__ __launch_bounds__(256) void ln_stats(const float* __restrict__ Xf,
                                                float* __restrict__ stats) {
    int wave = threadIdx.x >> 6, l = threadIdx.x & 63;
    int row = blockIdx.x * 4 + wave;
    f32x4 v = *(const f32x4*)(Xf + (long long)row * FIN + l * 4);
    float s = v[0] + v[1] + v[2] + v[3];
    float ss = v[0] * v[0] + v[1] * v[1] + v[2] * v[2] + v[3] * v[3];
#pragma unroll
    for (int m = 1; m < 64; m <<= 1) {
        s += __shfl_xor(s, m);
        ss += __shfl_xor(ss, m);
    }
    if (l == 0) {
        float mu = s * (1.0f / FIN);
        float var = ss * (1.0f / FIN) - mu * mu;
        f32x2 st;
        st.x = mu;
        st.y = rsqrtf(fmaxf(var, 0.f) + 1e-5f);
        *(f32x2*)&stats[row * 2] = st;
    }
}

// ---------------- gemm_v10: fp16 MFMA, A register-prefetched (single pass), W-half LDS ----------------
// T[M,N](fp16) = dis[r] * ((LNS? (Xf-mu)*rsig*lnw+lnb : Xh)[M,K] @ W[K,N])
// Fill (if enabled) runs at the TAIL: outside the barrier-coupled critical path.
template <int K, int N, int NH, bool LNS, bool FILL>
__global__ __launch_bounds__(512) void gemm_v10(
    const float* __restrict__ Xf, const u16* __restrict__ Xh, const u16* __restrict__ Wg,
    const float* __restrict__ lnw, const float* __restrict__ lnb,
    const float* __restrict__ stats, const float* __restrict__ dis, u16* __restrict__ Y,
    const int* __restrict__ src, const int* __restrict__ dst,
    const int* __restrict__ erank, const int* __restrict__ rowstart,
    int* __restrict__ csrc, int E) {
    constexpr int BM = 128;
    constexpr int NW = N / NH;
    constexpr int NT = NW / 16;
    constexpr int NK = K / 32;

    __shared__ u16 Wl[NW * K];

    const int t = threadIdx.x;
    int rb, hb;
    if (NH == 2) {
        int q = blockIdx.x & 15, g = blockIdx.x >> 4;
        rb = g * 8 + (q & 7);
        hb = q >> 3;
    } else {
        rb = blockIdx.x;
        hb = 0;
    }
    const int row0 = rb * BM;

    const int wave = t >> 6, l = t & 63;
    const int lm = l & 15, lq = l >> 4;
    const int row = row0 + wave * 16 + lm;

    // A prefetch: single pass, convert to fp16 regs
    f16x8 a[NK];
    if (LNS) {
        f32x2 st = *(const f32x2*)&stats[row * 2];
        const float* xr = Xf + (long long)row * K;
#pragma unroll
        for (int kk = 0; kk < NK; ++kk) {
            f32x4 x0 = *(const f32x4*)(xr + kk * 32 + lq * 8);
            f32x4 x1 = *(const f32x4*)(xr + kk * 32 + lq * 8 + 4);
            f32x4 w0 = *(const f32x4*)(lnw + kk * 32 + lq * 8);
            f32x4 w1 = *(const f32x4*)(lnw + kk * 32 + lq * 8 + 4);
            f32x4 c0 = *(const f32x4*)(lnb + kk * 32 + lq * 8);
            f32x4 c1 = *(const f32x4*)(lnb + kk * 32 + lq * 8 + 4);
#pragma unroll
            for (int c = 0; c < 4; ++c) {
                a[kk][c] = (_Float16)((x0[c] - st.x) * st.y * w0[c] + c0[c]);
                a[kk][4 + c] = (_Float16)((x1[c] - st.x) * st.y * w1[c] + c1[c]);
            }
        }
    } else {
#pragma unroll
        for (int kk = 0; kk < NK; ++kk)
            a[kk] = *(const f16x8*)&Xh[(long long)row * K + kk * 32 + lq * 8];
    }

    // stage W half: 16B granules, swizzle k8 by n&7
    for (int i = t; i < NW * (K / 8); i += 512) {
        int nn = i / (K / 8), k8 = i % (K / 8);
        *(uint4v*)&Wl[nn * K + ((k8 ^ (nn & 7)) * 8)] =
            *(const uint4v*)&Wg[(hb * NW + nn) * K + k8 * 8];
    }
    __syncthreads();

    f32x4 acc[NT];
#pragma unroll
    for (int i = 0; i < NT; ++i) acc[i] = (f32x4){0.f, 0.f, 0.f, 0.f};

#pragma unroll
    for (int kk = 0; kk < NK; ++kk) {
#pragma unroll
        for (int nt = 0; nt < NT; ++nt) {
            int nn = nt * 16 + lm;
            f16x8 wv = *(const f16x8*)&Wl[nn * K + (((kk * 4 + lq) ^ (nn & 7)) * 8)];
            acc[nt] = __builtin_amdgcn_mfma_f32_16x16x32_f16(wv, a[kk], acc[nt], 0, 0, 0);
        }
    }

    const float di = dis[row];
    u16* yr = Y + (long long)row * N + hb * NW;
#pragma unroll
    for (int nt = 0; nt < NT; ++nt) {
        f16x4 v;
#pragma unroll
        for (int r = 0; r < 4; ++r) v[r] = (_Float16)(acc[nt][r] * di);
        *(f16x4*)&yr[nt * 16 + lq * 4] = v;
    }

    if (FILL) {
        // tail-fused no-atomic csr fill: latency retires with the wave
        int epb = E / gridDim.x;
        int base = blockIdx.x * epb;
        for (int j = t; j < epb; j += 512) {
            int e = base + j;
            int d = dst[e];
            csrc[rowstart[d] + erank[e]] = src[e];
        }
    }
}

// ---------------- CSR gather F=128: out = relu(dis_d*(sum T_s + T_d) + b) ----------------
__global__ __launch_bounds__(256) void agg128h(
    const u16* __restrict__ T, const int* __restrict__ rowstart, const int* __restrict__ degv,
    const int* __restrict__ csrc, const float* __restrict__ dis, const float* __restrict__ bias,
    u16* __restrict__ OUT, int relu) {
    int node = blockIdx.x * 4 + (threadIdx.x >> 6);
    int l = threadIdx.x & 63;
    int h = l >> 4, c = l & 15;  // 4 edge slots x 16 lanes x 8 feats
    float di = dis[node];
    float acc[8] = {0.f, 0.f, 0.f, 0.f, 0.f, 0.f, 0.f, 0.f};
    if (h == 0) {
        f16x8 s = *(const f16x8*)&T[(long long)node * 128 + c * 8];
#pragma unroll
        for (int i = 0; i < 8; ++i) acc[i] = (float)s[i];
    }
    int e0 = rowstart[node];
    int e1 = e0 + degv[node];
    int e = e0 + h;
    for (; e + 4 < e1; e += 8) {
        int s0 = csrc[e], s1 = csrc[e + 4];
        f16x8 u0 = *(const f16x8*)&T[(long long)s0 * 128 + c * 8];
        f16x8 u1 = *(const f16x8*)&T[(long long)s1 * 128 + c * 8];
#pragma unroll
        for (int i = 0; i < 8; ++i) acc[i] += (float)u0[i] + (float)u1[i];
    }
    if (e < e1) {
        int s0 = csrc[e];
        f16x8 u0 = *(const f16x8*)&T[(long long)s0 * 128 + c * 8];
#pragma unroll
        for (int i = 0; i < 8; ++i) acc[i] += (float)u0[i];
    }
#pragma unroll
    for (int m = 16; m <= 32; m <<= 1) {
#pragma unroll
        for (int i = 0; i < 8; ++i) acc[i] += __shfl_xor(acc[i], m);
    }
    if (h == 0) {
        f32x4 b0 = *(const f32x4*)(bias + c * 8);
        f32x4 b1 = *(const f32x4*)(bias + c * 8 + 4);
        f16x8 r;
#pragma unroll
        for (int i = 0; i < 8; ++i) {
            float b = (i < 4) ? b0[i] : b1[i - 4];
            float v = acc[i] * di + b;
            if (relu) v = fmaxf(v, 0.f);
            r[i] = (_Float16)v;
        }
        *(f16x8*)&OUT[(long long)node * 128 + c * 8] = r;
    }
}

// ---------------- F=32 gather -> fp32 out ----------------
__global__ __launch_bounds__(256) void agg32h(
    const u16* __restrict__ T, const int* __restrict__ rowstart, const int* __restrict__ degv,
    const int* __restrict__ csrc, const float* __restrict__ dis, const float* __restrict__ bias,
    float* __restrict__ OUT) {
    int node = blockIdx.x * 4 + (threadIdx.x >> 6);
    int l = threadIdx.x & 63;
    int h = l >> 3, c = l & 7;  // 8 edge slots x 8 lanes x 4 feats
    float di = dis[node];
    f32x4 acc = (f32x4){0.f, 0.f, 0.f, 0.f};
    if (h == 0) {
        f16x4 s = *(const f16x4*)&T[(long long)node * 32 + c * 4];
#pragma unroll
        for (int i = 0; i < 4; ++i) acc[i] = (float)s[i];
    }
    int e0 = rowstart[node];
    int e1 = e0 + degv[node];
    int e = e0 + h;
    for (; e + 8 < e1; e += 16) {
        int s0 = csrc[e], s1 = csrc[e + 8];
        f16x4 u0 = *(const f16x4*)&T[(long long)s0 * 32 + c * 4];
        f16x4 u1 = *(const f16x4*)&T[(long long)s1 * 32 + c * 4];
#pragma unroll
        for (int i = 0; i < 4; ++i) acc[i] += (float)u0[i] + (float)u1[i];
    }
    if (e < e1) {
        int s0 = csrc[e];
        f16x4 u0 = *(const f16x4*)&T[(long long)s0 * 32 + c * 4];
#pragma unroll
        for (int i = 0; i < 4; ++i) acc[i] += (float)u0[i];
    }
#pragma unroll
    for (int m = 8; m <= 32; m <<= 1) {
#pragma unroll
        for (int i = 0; i < 4; ++i) acc[i] += __shfl_xor(acc[i], m);
    }
    if (h == 0) {
        f32x4 b0 = *(const f32x4*)(bias + c * 4);
        f32x4 r;
#pragma unroll
        for (int i = 0; i < 4; ++i) r[i] = acc[i] * di + b0[i];
        *(f32x4*)(OUT + (long long)node * 32 + c * 4) = r;
    }
}

extern "C" void kernel_launch(void* const* d_in, const int* in_sizes, int n_in,
                              void* d_out, int out_size, void* d_ws, size_t ws_size,
                              hipStream_t stream) {
    const float* x = (const float*)d_in[0];
    const int* ei = (const int*)d_in[1];
    const float* lnw = (const float*)d_in[2];
    const float* lnb = (const float*)d_in[3];
    const float* W1 = (const float*)d_in[4];
    const float* b1 = (const float*)d_in[5];
    const float* W2 = (const float*)d_in[6];
    const float* b2 = (const float*)d_in[7];
    const float* W3 = (const float*)d_in[8];
    const float* b3 = (const float*)d_in[9];
    float* out = (float*)d_out;

    const int n = in_sizes[0] / FIN;  // 65536
    const int E = in_sizes[1] / 2;    // 524288
    const int* src = ei;
    const int* dst = ei + E;

    char* w = (char*)d_ws;
    auto alloc = [&](size_t bytes) {
        char* p = w;
        w += (bytes + 255) & ~(size_t)255;
        return p;
    };
    int* deg = (int*)alloc((size_t)n * 4);
    int* rowstart = (int*)alloc((size_t)n * 4);
    int* erank = (int*)alloc((size_t)E * 4);
    int* total = (int*)alloc(256);
    float* dis = (float*)alloc((size_t)n * 4);
    float* stats = (float*)alloc((size_t)n * 2 * 4);
    int* csrc = (int*)alloc((size_t)E * 4);
    u16* w1h = (u16*)alloc(FIN * FH * 2);
    u16* w2h = (u16*)alloc(FH * FH * 2);
    u16* w3h = (u16*)alloc(FH * FZ * 2);
    u16* bufA = (u16*)alloc((size_t)n * FH * 2);
    u16* bufB = (u16*)alloc((size_t)n * FH * 2);

    // 1) prep: zero deg/total + weight convert (Wt[N][K] fp16)
    prep<<<464, 256, 0, stream>>>(W1, W2, W3, w1h, w2h, w3h, deg, total);
    // 2) degree histogram + edge ranks
    deg_count<<<E / 256, 256, 0, stream>>>(dst, deg, erank, E);
    // 3) single-kernel scan + dis
    scan_fused<<<n / 256, 256, 0, stream>>>(deg, total, rowstart, dis);
    // 4) LN stats (coalesced streaming pass, stats only)
    ln_stats<<<n / 4, 256, 0, stream>>>(x, stats);
    // 5) conv1 GEMM (LN-apply from stats, dis-fold, N-halved) with tail-fused no-atomic csr fill
    gemm_v10<256, 128, 2, true, true><<<(n / 128) * 2, 512, 0, stream>>>(
        x, nullptr, w1h, lnw, lnb, stats, dis, bufA, src, dst, erank, rowstart, csrc, E);
    // 6) conv1 aggregate
    agg128h<<<n / 4, 256, 0, stream>>>(bufA, rowstart, deg, csrc, dis, b1, bufB, 1);
    // 7) conv2 GEMM (N-halved)
    gemm_v10<128, 128, 2, false, false><<<(n / 128) * 2, 512, 0, stream>>>(
        nullptr, bufB, w2h, nullptr, nullptr, nullptr, dis, bufA, nullptr, nullptr, nullptr, nullptr, nullptr, 0);
    // 8) conv2 aggregate
    agg128h<<<n / 4, 256, 0, stream>>>(bufA, rowstart, deg, csrc, dis, b2, bufB, 1);
    // 9) conv3 GEMM
    gemm_v10<128, 32, 1, false, false><<<n / 128, 512, 0, stream>>>(
        nullptr, bufB, w3h, nullptr, nullptr, nullptr, dis, bufA, nullptr, nullptr, nullptr, nullptr, nullptr, 0);
    // 10) conv3 aggregate -> out
    agg32h<<<n / 4, 256, 0, stream>>>(bufA, rowstart, deg, csrc, dis, b3, out);
}

// Round 15
// 180.688 us; speedup vs baseline: 1.1080x; 1.1080x over previous
//
#include <hip/hip_runtime.h>
#include <hip/hip_bf16.h>

#define FIN 256
#define FH 128
#define FZ 32

typedef unsigned short u16;
typedef unsigned int u32;
typedef __attribute__((ext_vector_type(4))) float f32x4;
typedef __attribute__((ext_vector_type(8))) _Float16 f16x8;
typedef __attribute__((ext_vector_type(4))) _Float16 f16x4;
typedef __attribute__((ext_vector_type(4))) unsigned int uint4v;

__device__ inline u16 f2h(float v) { return __builtin_bit_cast(u16, (_Float16)v); }

// ---------------- prep: zero deg/total + weight convert to fp16 Wt[N][K] ----------------
__global__ __launch_bounds__(256) void prep(const float* __restrict__ W1,
                                            const float* __restrict__ W2,
                                            const float* __restrict__ W3,
                                            u16* __restrict__ w1h, u16* __restrict__ w2h,
                                            u16* __restrict__ w3h, int* __restrict__ deg,
                                            int* __restrict__ total) {
    int b = blockIdx.x, t = threadIdx.x;
    if (b < 256) {
        deg[b * 256 + t] = 0;
        if (b == 0 && t == 0) *total = 0;
        return;
    }
    int i = (b - 256) * 256 + t;
    if (i < FIN * FH) {
        int k = i / FH, n = i % FH;
        w1h[n * FIN + k] = f2h(W1[i]);
    } else if (i < FIN * FH + FH * FH) {
        int j = i - FIN * FH;
        int k = j / FH, n = j % FH;
        w2h[n * FH + k] = f2h(W2[j]);
    } else {
        int j = i - (FIN * FH + FH * FH);
        int k = j / FZ, n = j % FZ;
        w3h[n * FH + k] = f2h(W3[j]);
    }
}

// ---------------- degree count + per-edge rank (atomic return value) ----------------
__global__ void deg_count(const int* __restrict__ dst, int* __restrict__ deg,
                          int* __restrict__ erank, int E) {
    int e = blockIdx.x * 256 + threadIdx.x;
    if (e < E) erank[e] = atomicAdd(&deg[dst[e]], 1);
}

// ---------------- single-kernel scan: block-local scan + atomic base ----------------
__global__ __launch_bounds__(256) void scan_fused(const int* __restrict__ deg,
                                                  int* __restrict__ total,
                                                  int* __restrict__ rowstart,
                                                  float* __restrict__ dis) {
    __shared__ int s[256];
    __shared__ int base;
    int t = threadIdx.x;
    int i = blockIdx.x * 256 + t;
    int v = deg[i];
    s[t] = v;
    __syncthreads();
    for (int o = 1; o < 256; o <<= 1) {
        int add = (t >= o) ? s[t - o] : 0;
        __syncthreads();
        s[t] += add;
        __syncthreads();
    }
    if (t == 255) base = atomicAdd(total, s[255]);
    __syncthreads();
    rowstart[i] = s[t] - v + base;
    dis[i] = rsqrtf((float)v + 1.0f);
}

// ---------------- gemm_v9 (NH=1 geometry): fp16 MFMA, full W LDS-resident, fused LN + fill ----------------
// T[M,N](fp16) = dis[r] * ((LN? LayerNorm(Xf) : Xh)[M,K] @ W[K,N])
// LN: pass1 stats (2 live regs) -> pass2 re-read (L2-hot) to fp16 regs. Non-LN: A prefetched.
// Swapped-operand MFMA: lane holds 4 consecutive cols of one row -> contiguous 8B stores.
template <int K, int N, int NH, bool LN, bool FILL>
__global__ __launch_bounds__(512) void gemm_v9(
    const float* __restrict__ Xf, const u16* __restrict__ Xh, const u16* __restrict__ Wg,
    const float* __restrict__ lnw, const float* __restrict__ lnb,
    const float* __restrict__ dis, u16* __restrict__ Y,
    const int* __restrict__ src, const int* __restrict__ dst,
    const int* __restrict__ erank, const int* __restrict__ rowstart,
    int* __restrict__ csrc, int E) {
    constexpr int BM = 128;
    constexpr int NW = N / NH;
    constexpr int NT = NW / 16;
    constexpr int NK = K / 32;

    __shared__ u16 Wl[NW * K];

    const int t = threadIdx.x;
    int rb, hb;
    if (NH == 2) {
        int q = blockIdx.x & 15, g = blockIdx.x >> 4;
        rb = g * 8 + (q & 7);
        hb = q >> 3;
    } else {
        rb = blockIdx.x;
        hb = 0;
    }
    const int row0 = rb * BM;

    const int wave = t >> 6, l = t & 63;
    const int lm = l & 15, lq = l >> 4;
    const int row = row0 + wave * 16 + lm;

    float mu = 0.f, rs = 1.f;
    f16x8 a[NK];
    if (LN) {
        // pass 1: stats only
        const float* xr = Xf + (long long)row * K;
        float s = 0.f, ss = 0.f;
#pragma unroll
        for (int kk = 0; kk < NK; ++kk) {
            f32x4 x0 = *(const f32x4*)(xr + kk * 32 + lq * 8);
            f32x4 x1 = *(const f32x4*)(xr + kk * 32 + lq * 8 + 4);
#pragma unroll
            for (int c = 0; c < 4; ++c) {
                s += x0[c] + x1[c];
                ss += x0[c] * x0[c] + x1[c] * x1[c];
            }
        }
        s += __shfl_xor(s, 16);
        ss += __shfl_xor(ss, 16);
        s += __shfl_xor(s, 32);
        ss += __shfl_xor(ss, 32);
        mu = s * (1.0f / K);
        rs = rsqrtf(fmaxf(ss * (1.0f / K) - mu * mu, 0.f) + 1e-5f);
    } else {
#pragma unroll
        for (int kk = 0; kk < NK; ++kk)
            a[kk] = *(const f16x8*)&Xh[(long long)row * K + kk * 32 + lq * 8];
    }

    if (FILL) {
        int epb = E / gridDim.x;
        int base = blockIdx.x * epb;
        for (int j = t; j < epb; j += 512) {
            int e = base + j;
            int d = dst[e];
            csrc[rowstart[d] + erank[e]] = src[e];
        }
    }

    // stage W: 16B granules, swizzle k8 by n&7
    for (int i = t; i < NW * (K / 8); i += 512) {
        int nn = i / (K / 8), k8 = i % (K / 8);
        *(uint4v*)&Wl[nn * K + ((k8 ^ (nn & 7)) * 8)] =
            *(const uint4v*)&Wg[(hb * NW + nn) * K + k8 * 8];
    }

    if (LN) {
        // pass 2: re-read (L2-hot) and convert
        const float* xr = Xf + (long long)row * K;
#pragma unroll
        for (int kk = 0; kk < NK; ++kk) {
            f32x4 x0 = *(const f32x4*)(xr + kk * 32 + lq * 8);
            f32x4 x1 = *(const f32x4*)(xr + kk * 32 + lq * 8 + 4);
            f32x4 w0 = *(const f32x4*)(lnw + kk * 32 + lq * 8);
            f32x4 w1 = *(const f32x4*)(lnw + kk * 32 + lq * 8 + 4);
            f32x4 c0 = *(const f32x4*)(lnb + kk * 32 + lq * 8);
            f32x4 c1 = *(const f32x4*)(lnb + kk * 32 + lq * 8 + 4);
#pragma unroll
            for (int c = 0; c < 4; ++c) {
                a[kk][c] = (_Float16)((x0[c] - mu) * rs * w0[c] + c0[c]);
                a[kk][4 + c] = (_Float16)((x1[c] - mu) * rs * w1[c] + c1[c]);
            }
        }
    }
    __syncthreads();

    f32x4 acc[NT];
#pragma unroll
    for (int i = 0; i < NT; ++i) acc[i] = (f32x4){0.f, 0.f, 0.f, 0.f};

#pragma unroll
    for (int kk = 0; kk < NK; ++kk) {
#pragma unroll
        for (int nt = 0; nt < NT; ++nt) {
            int nn = nt * 16 + lm;
            f16x8 wv = *(const f16x8*)&Wl[nn * K + (((kk * 4 + lq) ^ (nn & 7)) * 8)];
            acc[nt] = __builtin_amdgcn_mfma_f32_16x16x32_f16(wv, a[kk], acc[nt], 0, 0, 0);
        }
    }

    const float di = dis[row];
    u16* yr = Y + (long long)row * N + hb * NW;
#pragma unroll
    for (int nt = 0; nt < NT; ++nt) {
        f16x4 v;
#pragma unroll
        for (int r = 0; r < 4; ++r) v[r] = (_Float16)(acc[nt][r] * di);
        *(f16x4*)&yr[nt * 16 + lq * 4] = v;
    }
}

// ---------------- CSR gather F=128: out = relu(dis_d*(sum T_s + T_d) + b) ----------------
__global__ __launch_bounds__(256) void agg128h(
    const u16* __restrict__ T, const int* __restrict__ rowstart, const int* __restrict__ degv,
    const int* __restrict__ csrc, const float* __restrict__ dis, const float* __restrict__ bias,
    u16* __restrict__ OUT, int relu) {
    int node = blockIdx.x * 4 + (threadIdx.x >> 6);
    int l = threadIdx.x & 63;
    int h = l >> 4, c = l & 15;  // 4 edge slots x 16 lanes x 8 feats
    float di = dis[node];
    float acc[8] = {0.f, 0.f, 0.f, 0.f, 0.f, 0.f, 0.f, 0.f};
    if (h == 0) {
        f16x8 s = *(const f16x8*)&T[(long long)node * 128 + c * 8];
#pragma unroll
        for (int i = 0; i < 8; ++i) acc[i] = (float)s[i];
    }
    int e0 = rowstart[node];
    int e1 = e0 + degv[node];
    int e = e0 + h;
    for (; e + 4 < e1; e += 8) {
        int s0 = csrc[e], s1 = csrc[e + 4];
        f16x8 u0 = *(const f16x8*)&T[(long long)s0 * 128 + c * 8];
        f16x8 u1 = *(const f16x8*)&T[(long long)s1 * 128 + c * 8];
#pragma unroll
        for (int i = 0; i < 8; ++i) acc[i] += (float)u0[i] + (float)u1[i];
    }
    if (e < e1) {
        int s0 = csrc[e];
        f16x8 u0 = *(const f16x8*)&T[(long long)s0 * 128 + c * 8];
#pragma unroll
        for (int i = 0; i < 8; ++i) acc[i] += (float)u0[i];
    }
#pragma unroll
    for (int m = 16; m <= 32; m <<= 1) {
#pragma unroll
        for (int i = 0; i < 8; ++i) acc[i] += __shfl_xor(acc[i], m);
    }
    if (h == 0) {
        f32x4 b0 = *(const f32x4*)(bias + c * 8);
        f32x4 b1 = *(const f32x4*)(bias + c * 8 + 4);
        f16x8 r;
#pragma unroll
        for (int i = 0; i < 8; ++i) {
            float b = (i < 4) ? b0[i] : b1[i - 4];
            float v = acc[i] * di + b;
            if (relu) v = fmaxf(v, 0.f);
            r[i] = (_Float16)v;
        }
        *(f16x8*)&OUT[(long long)node * 128 + c * 8] = r;
    }
}

// ---------------- F=32 gather -> fp32 out ----------------
__global__ __launch_bounds__(256) void agg32h(
    const u16* __restrict__ T, const int* __restrict__ rowstart, const int* __restrict__ degv,
    const int* __restrict__ csrc, const float* __restrict__ dis, const float* __restrict__ bias,
    float* __restrict__ OUT) {
    int node = blockIdx.x * 4 + (threadIdx.x >> 6);
    int l = threadIdx.x & 63;
    int h = l >> 3, c = l & 7;  // 8 edge slots x 8 lanes x 4 feats
    float di = dis[node];
    f32x4 acc = (f32x4){0.f, 0.f, 0.f, 0.f};
    if (h == 0) {
        f16x4 s = *(const f16x4*)&T[(long long)node * 32 + c * 4];
#pragma unroll
        for (int i = 0; i < 4; ++i) acc[i] = (float)s[i];
    }
    int e0 = rowstart[node];
    int e1 = e0 + degv[node];
    int e = e0 + h;
    for (; e + 8 < e1; e += 16) {
        int s0 = csrc[e], s1 = csrc[e + 8];
        f16x4 u0 = *(const f16x4*)&T[(long long)s0 * 32 + c * 4];
        f16x4 u1 = *(const f16x4*)&T[(long long)s1 * 32 + c * 4];
#pragma unroll
        for (int i = 0; i < 4; ++i) acc[i] += (float)u0[i] + (float)u1[i];
    }
    if (e < e1) {
        int s0 = csrc[e];
        f16x4 u0 = *(const f16x4*)&T[(long long)s0 * 32 + c * 4];
#pragma unroll
        for (int i = 0; i < 4; ++i) acc[i] += (float)u0[i];
    }
#pragma unroll
    for (int m = 8; m <= 32; m <<= 1) {
#pragma unroll
        for (int i = 0; i < 4; ++i) acc[i] += __shfl_xor(acc[i], m);
    }
    if (h == 0) {
        f32x4 b0 = *(const f32x4*)(bias + c * 4);
        f32x4 r;
#pragma unroll
        for (int i = 0; i < 4; ++i) r[i] = acc[i] * di + b0[i];
        *(f32x4*)(OUT + (long long)node * 32 + c * 4) = r;
    }
}

extern "C" void kernel_launch(void* const* d_in, const int* in_sizes, int n_in,
                              void* d_out, int out_size, void* d_ws, size_t ws_size,
                              hipStream_t stream) {
    const float* x = (const float*)d_in[0];
    const int* ei = (const int*)d_in[1];
    const float* lnw = (const float*)d_in[2];
    const float* lnb = (const float*)d_in[3];
    const float* W1 = (const float*)d_in[4];
    const float* b1 = (const float*)d_in[5];
    const float* W2 = (const float*)d_in[6];
    const float* b2 = (const float*)d_in[7];
    const float* W3 = (const float*)d_in[8];
    const float* b3 = (const float*)d_in[9];
    float* out = (float*)d_out;

    const int n = in_sizes[0] / FIN;  // 65536
    const int E = in_sizes[1] / 2;    // 524288
    const int* src = ei;
    const int* dst = ei + E;

    char* w = (char*)d_ws;
    auto alloc = [&](size_t bytes) {
        char* p = w;
        w += (bytes + 255) & ~(size_t)255;
        return p;
    };
    int* deg = (int*)alloc((size_t)n * 4);
    int* rowstart = (int*)alloc((size_t)n * 4);
    int* erank = (int*)alloc((size_t)E * 4);
    int* total = (int*)alloc(256);
    float* dis = (float*)alloc((size_t)n * 4);
    int* csrc = (int*)alloc((size_t)E * 4);
    u16* w1h = (u16*)alloc(FIN * FH * 2);
    u16* w2h = (u16*)alloc(FH * FH * 2);
    u16* w3h = (u16*)alloc(FH * FZ * 2);
    u16* bufA = (u16*)alloc((size_t)n * FH * 2);
    u16* bufB = (u16*)alloc((size_t)n * FH * 2);

    // 1) prep: zero deg/total + weight convert (Wt[N][K] fp16)
    prep<<<464, 256, 0, stream>>>(W1, W2, W3, w1h, w2h, w3h, deg, total);
    // 2) degree histogram + edge ranks
    deg_count<<<E / 256, 256, 0, stream>>>(dst, deg, erank, E);
    // 3) single-kernel scan + dis
    scan_fused<<<n / 256, 256, 0, stream>>>(deg, total, rowstart, dis);
    // 4) conv1 GEMM (fused LN, dis-fold, FULL-W LDS) with head-fused no-atomic csr fill
    gemm_v9<256, 128, 1, true, true><<<n / 128, 512, 0, stream>>>(
        x, nullptr, w1h, lnw, lnb, dis, bufA, src, dst, erank, rowstart, csrc, E);
    // 5) conv1 aggregate
    agg128h<<<n / 4, 256, 0, stream>>>(bufA, rowstart, deg, csrc, dis, b1, bufB, 1);
    // 6) conv2 GEMM (full-W LDS, A-prefetch)
    gemm_v9<128, 128, 1, false, false><<<n / 128, 512, 0, stream>>>(
        nullptr, bufB, w2h, nullptr, nullptr, dis, bufA, nullptr, nullptr, nullptr, nullptr, nullptr, 0);
    // 7) conv2 aggregate
    agg128h<<<n / 4, 256, 0, stream>>>(bufA, rowstart, deg, csrc, dis, b2, bufB, 1);
    // 8) conv3 GEMM
    gemm_v9<128, 32, 1, false, false><<<n / 128, 512, 0, stream>>>(
        nullptr, bufB, w3h, nullptr, nullptr, dis, bufA, nullptr, nullptr, nullptr, nullptr, nullptr, 0);
    // 9) conv3 aggregate -> out
    agg32h<<<n / 4, 256, 0, stream>>>(bufA, rowstart, deg, csrc, dis, b3, out);
}

// Round 16
// 154.357 us; speedup vs baseline: 1.2970x; 1.1706x over previous
//
#include <hip/hip_runtime.h>
#include <hip/hip_bf16.h>

#define FIN 256
#define FH 128
#define FZ 32

typedef unsigned short u16;
typedef unsigned int u32;
typedef __attribute__((ext_vector_type(4))) float f32x4;
typedef __attribute__((ext_vector_type(8))) _Float16 f16x8;
typedef __attribute__((ext_vector_type(4))) _Float16 f16x4;
typedef __attribute__((ext_vector_type(4))) unsigned int uint4v;

__device__ inline u16 f2h(float v) { return __builtin_bit_cast(u16, (_Float16)v); }

// ---------------- prep: zero deg/total + weight convert to fp16 Wt[N][K] ----------------
__global__ __launch_bounds__(256) void prep(const float* __restrict__ W1,
                                            const float* __restrict__ W2,
                                            const float* __restrict__ W3,
                                            u16* __restrict__ w1h, u16* __restrict__ w2h,
                                            u16* __restrict__ w3h, int* __restrict__ deg,
                                            int* __restrict__ total) {
    int b = blockIdx.x, t = threadIdx.x;
    if (b < 256) {
        deg[b * 256 + t] = 0;
        if (b == 0 && t == 0) *total = 0;
        return;
    }
    int i = (b - 256) * 256 + t;
    if (i < FIN * FH) {
        int k = i / FH, n = i % FH;
        w1h[n * FIN + k] = f2h(W1[i]);
    } else if (i < FIN * FH + FH * FH) {
        int j = i - FIN * FH;
        int k = j / FH, n = j % FH;
        w2h[n * FH + k] = f2h(W2[j]);
    } else {
        int j = i - (FIN * FH + FH * FH);
        int k = j / FZ, n = j % FZ;
        w3h[n * FH + k] = f2h(W3[j]);
    }
}

// ---------------- degree count + per-edge rank (atomic return value) ----------------
__global__ void deg_count(const int* __restrict__ dst, int* __restrict__ deg,
                          int* __restrict__ erank, int E) {
    int e = blockIdx.x * 256 + threadIdx.x;
    if (e < E) erank[e] = atomicAdd(&deg[dst[e]], 1);
}

// ---------------- single-kernel scan: block-local scan + atomic base ----------------
__global__ __launch_bounds__(256) void scan_fused(const int* __restrict__ deg,
                                                  int* __restrict__ total,
                                                  int* __restrict__ rowstart,
                                                  float* __restrict__ dis) {
    __shared__ int s[256];
    __shared__ int base;
    int t = threadIdx.x;
    int i = blockIdx.x * 256 + t;
    int v = deg[i];
    s[t] = v;
    __syncthreads();
    for (int o = 1; o < 256; o <<= 1) {
        int add = (t >= o) ? s[t - o] : 0;
        __syncthreads();
        s[t] += add;
        __syncthreads();
    }
    if (t == 255) base = atomicAdd(total, s[255]);
    __syncthreads();
    rowstart[i] = s[t] - v + base;
    dis[i] = rsqrtf((float)v + 1.0f);
}

// ---------------- conv1 GEMM: fp16 MFMA, full W LDS, fused LN (2-pass) + head-fused fill ----------------
__global__ __launch_bounds__(512) void gemm_ln(
    const float* __restrict__ Xf, const u16* __restrict__ Wg,
    const float* __restrict__ lnw, const float* __restrict__ lnb,
    const float* __restrict__ dis, u16* __restrict__ Y,
    const int* __restrict__ src, const int* __restrict__ dst,
    const int* __restrict__ erank, const int* __restrict__ rowstart,
    int* __restrict__ csrc, int E) {
    constexpr int K = FIN, N = FH;
    constexpr int BM = 128, NT = N / 16, NK = K / 32;

    __shared__ u16 Wl[N * K];

    const int t = threadIdx.x;
    const int row0 = blockIdx.x * BM;
    const int wave = t >> 6, l = t & 63;
    const int lm = l & 15, lq = l >> 4;
    const int row = row0 + wave * 16 + lm;

    // pass 1: LN stats
    const float* xr = Xf + (long long)row * K;
    float s = 0.f, ss = 0.f;
#pragma unroll
    for (int kk = 0; kk < NK; ++kk) {
        f32x4 x0 = *(const f32x4*)(xr + kk * 32 + lq * 8);
        f32x4 x1 = *(const f32x4*)(xr + kk * 32 + lq * 8 + 4);
#pragma unroll
        for (int c = 0; c < 4; ++c) {
            s += x0[c] + x1[c];
            ss += x0[c] * x0[c] + x1[c] * x1[c];
        }
    }
    s += __shfl_xor(s, 16);
    ss += __shfl_xor(ss, 16);
    s += __shfl_xor(s, 32);
    ss += __shfl_xor(ss, 32);
    float mu = s * (1.0f / K);
    float rs = rsqrtf(fmaxf(ss * (1.0f / K) - mu * mu, 0.f) + 1e-5f);

    // head-fused no-atomic csr fill
    {
        int epb = E / gridDim.x;
        int base = blockIdx.x * epb;
        for (int j = t; j < epb; j += 512) {
            int e = base + j;
            int d = dst[e];
            csrc[rowstart[d] + erank[e]] = src[e];
        }
    }

    // stage W (swizzled)
    for (int i = t; i < N * K / 8; i += 512) {
        int nn = i / (K / 8), k8 = i % (K / 8);
        *(uint4v*)&Wl[nn * K + ((k8 ^ (nn & 7)) * 8)] = *(const uint4v*)&Wg[nn * K + k8 * 8];
    }

    // pass 2: re-read (L2-hot), normalize, convert
    f16x8 a[NK];
#pragma unroll
    for (int kk = 0; kk < NK; ++kk) {
        f32x4 x0 = *(const f32x4*)(xr + kk * 32 + lq * 8);
        f32x4 x1 = *(const f32x4*)(xr + kk * 32 + lq * 8 + 4);
        f32x4 w0 = *(const f32x4*)(lnw + kk * 32 + lq * 8);
        f32x4 w1 = *(const f32x4*)(lnw + kk * 32 + lq * 8 + 4);
        f32x4 c0 = *(const f32x4*)(lnb + kk * 32 + lq * 8);
        f32x4 c1 = *(const f32x4*)(lnb + kk * 32 + lq * 8 + 4);
#pragma unroll
        for (int c = 0; c < 4; ++c) {
            a[kk][c] = (_Float16)((x0[c] - mu) * rs * w0[c] + c0[c]);
            a[kk][4 + c] = (_Float16)((x1[c] - mu) * rs * w1[c] + c1[c]);
        }
    }
    __syncthreads();

    f32x4 acc[NT];
#pragma unroll
    for (int i = 0; i < NT; ++i) acc[i] = (f32x4){0.f, 0.f, 0.f, 0.f};
#pragma unroll
    for (int kk = 0; kk < NK; ++kk) {
#pragma unroll
        for (int nt = 0; nt < NT; ++nt) {
            int nn = nt * 16 + lm;
            f16x8 wv = *(const f16x8*)&Wl[nn * K + (((kk * 4 + lq) ^ (nn & 7)) * 8)];
            acc[nt] = __builtin_amdgcn_mfma_f32_16x16x32_f16(wv, a[kk], acc[nt], 0, 0, 0);
        }
    }

    const float di = dis[row];
    u16* yr = Y + (long long)row * N;
#pragma unroll
    for (int nt = 0; nt < NT; ++nt) {
        f16x4 v;
#pragma unroll
        for (int r = 0; r < 4; ++r) v[r] = (_Float16)(acc[nt][r] * di);
        *(f16x4*)&yr[nt * 16 + lq * 4] = v;
    }
}

// ---------------- gather_gemm: fused CSR-gather aggregation + GEMM ----------------
// h[row] = relu(dis[row] * (sum_{s in N(row)} T[s] + T[row]) + b)   (fp32, in-register)
// Y[row] = dis[row] * (h[row] @ W)                                  (fp16 out)
template <int K, int N>
__global__ __launch_bounds__(512) void gather_gemm(
    const u16* __restrict__ T, const u16* __restrict__ Wg,
    const int* __restrict__ rowstart, const int* __restrict__ degv,
    const int* __restrict__ csrc, const float* __restrict__ dis,
    const float* __restrict__ bias, u16* __restrict__ Y) {
    constexpr int BM = 128, NT = N / 16, NK = K / 32;

    __shared__ u16 Wl[N * K];
    __shared__ float bl[K];

    const int t = threadIdx.x;
    const int row0 = blockIdx.x * BM;
    const int wave = t >> 6, l = t & 63;
    const int lm = l & 15, lq = l >> 4;
    const int row = row0 + wave * 16 + lm;

    // stage W (swizzled) + bias
    for (int i = t; i < N * K / 8; i += 512) {
        int nn = i / (K / 8), k8 = i % (K / 8);
        *(uint4v*)&Wl[nn * K + ((k8 ^ (nn & 7)) * 8)] = *(const uint4v*)&Wg[nn * K + k8 * 8];
    }
    if (t < K / 4) *(f32x4*)&bl[t * 4] = *(const f32x4*)&bias[t * 4];

    // gather this row's aggregate into fp32 regs (4 lanes per row, 16B slices)
    const float di = dis[row];
    const int rs = rowstart[row], dg = degv[row];
    float g[NK][8];
    {
        const u16* tr = T + (long long)row * K;
#pragma unroll
        for (int kk = 0; kk < NK; ++kk) {
            f16x8 v = *(const f16x8*)&tr[kk * 32 + lq * 8];
#pragma unroll
            for (int j = 0; j < 8; ++j) g[kk][j] = (float)v[j];
        }
    }
    int e = rs, e1 = rs + dg;
    for (; e + 1 < e1; e += 2) {
        int s0 = csrc[e], s1 = csrc[e + 1];
        const u16* t0 = T + (long long)s0 * K;
        const u16* t1 = T + (long long)s1 * K;
#pragma unroll
        for (int kk = 0; kk < NK; ++kk) {
            f16x8 v0 = *(const f16x8*)&t0[kk * 32 + lq * 8];
            f16x8 v1 = *(const f16x8*)&t1[kk * 32 + lq * 8];
#pragma unroll
            for (int j = 0; j < 8; ++j) g[kk][j] += (float)v0[j] + (float)v1[j];
        }
    }
    if (e < e1) {
        const u16* t0 = T + (long long)csrc[e] * K;
#pragma unroll
        for (int kk = 0; kk < NK; ++kk) {
            f16x8 v0 = *(const f16x8*)&t0[kk * 32 + lq * 8];
#pragma unroll
            for (int j = 0; j < 8; ++j) g[kk][j] += (float)v0[j];
        }
    }
    __syncthreads();

    // h = relu(g*di + b) -> fp16 fragments
    f16x8 a[NK];
#pragma unroll
    for (int kk = 0; kk < NK; ++kk) {
#pragma unroll
        for (int j = 0; j < 8; ++j) {
            float h = fmaxf(g[kk][j] * di + bl[kk * 32 + lq * 8 + j], 0.f);
            a[kk][j] = (_Float16)h;
        }
    }

    f32x4 acc[NT];
#pragma unroll
    for (int i = 0; i < NT; ++i) acc[i] = (f32x4){0.f, 0.f, 0.f, 0.f};
#pragma unroll
    for (int kk = 0; kk < NK; ++kk) {
#pragma unroll
        for (int nt = 0; nt < NT; ++nt) {
            int nn = nt * 16 + lm;
            f16x8 wv = *(const f16x8*)&Wl[nn * K + (((kk * 4 + lq) ^ (nn & 7)) * 8)];
            acc[nt] = __builtin_amdgcn_mfma_f32_16x16x32_f16(wv, a[kk], acc[nt], 0, 0, 0);
        }
    }

    u16* yr = Y + (long long)row * N;
#pragma unroll
    for (int nt = 0; nt < NT; ++nt) {
        f16x4 v;
#pragma unroll
        for (int r = 0; r < 4; ++r) v[r] = (_Float16)(acc[nt][r] * di);
        *(f16x4*)&yr[nt * 16 + lq * 4] = v;
    }
}

// ---------------- F=32 gather -> fp32 out ----------------
__global__ __launch_bounds__(256) void agg32h(
    const u16* __restrict__ T, const int* __restrict__ rowstart, const int* __restrict__ degv,
    const int* __restrict__ csrc, const float* __restrict__ dis, const float* __restrict__ bias,
    float* __restrict__ OUT) {
    int node = blockIdx.x * 4 + (threadIdx.x >> 6);
    int l = threadIdx.x & 63;
    int h = l >> 3, c = l & 7;  // 8 edge slots x 8 lanes x 4 feats
    float di = dis[node];
    f32x4 acc = (f32x4){0.f, 0.f, 0.f, 0.f};
    if (h == 0) {
        f16x4 s = *(const f16x4*)&T[(long long)node * 32 + c * 4];
#pragma unroll
        for (int i = 0; i < 4; ++i) acc[i] = (float)s[i];
    }
    int e0 = rowstart[node];
    int e1 = e0 + degv[node];
    int e = e0 + h;
    for (; e + 8 < e1; e += 16) {
        int s0 = csrc[e], s1 = csrc[e + 8];
        f16x4 u0 = *(const f16x4*)&T[(long long)s0 * 32 + c * 4];
        f16x4 u1 = *(const f16x4*)&T[(long long)s1 * 32 + c * 4];
#pragma unroll
        for (int i = 0; i < 4; ++i) acc[i] += (float)u0[i] + (float)u1[i];
    }
    if (e < e1) {
        int s0 = csrc[e];
        f16x4 u0 = *(const f16x4*)&T[(long long)s0 * 32 + c * 4];
#pragma unroll
        for (int i = 0; i < 4; ++i) acc[i] += (float)u0[i];
    }
#pragma unroll
    for (int m = 8; m <= 32; m <<= 1) {
#pragma unroll
        for (int i = 0; i < 4; ++i) acc[i] += __shfl_xor(acc[i], m);
    }
    if (h == 0) {
        f32x4 b0 = *(const f32x4*)(bias + c * 4);
        f32x4 r;
#pragma unroll
        for (int i = 0; i < 4; ++i) r[i] = acc[i] * di + b0[i];
        *(f32x4*)(OUT + (long long)node * 32 + c * 4) = r;
    }
}

extern "C" void kernel_launch(void* const* d_in, const int* in_sizes, int n_in,
                              void* d_out, int out_size, void* d_ws, size_t ws_size,
                              hipStream_t stream) {
    const float* x = (const float*)d_in[0];
    const int* ei = (const int*)d_in[1];
    const float* lnw = (const float*)d_in[2];
    const float* lnb = (const float*)d_in[3];
    const float* W1 = (const float*)d_in[4];
    const float* b1 = (const float*)d_in[5];
    const float* W2 = (const float*)d_in[6];
    const float* b2 = (const float*)d_in[7];
    const float* W3 = (const float*)d_in[8];
    const float* b3 = (const float*)d_in[9];
    float* out = (float*)d_out;

    const int n = in_sizes[0] / FIN;  // 65536
    const int E = in_sizes[1] / 2;    // 524288
    const int* src = ei;
    const int* dst = ei + E;

    char* w = (char*)d_ws;
    auto alloc = [&](size_t bytes) {
        char* p = w;
        w += (bytes + 255) & ~(size_t)255;
        return p;
    };
    int* deg = (int*)alloc((size_t)n * 4);
    int* rowstart = (int*)alloc((size_t)n * 4);
    int* erank = (int*)alloc((size_t)E * 4);
    int* total = (int*)alloc(256);
    float* dis = (float*)alloc((size_t)n * 4);
    int* csrc = (int*)alloc((size_t)E * 4);
    u16* w1h = (u16*)alloc(FIN * FH * 2);
    u16* w2h = (u16*)alloc(FH * FH * 2);
    u16* w3h = (u16*)alloc(FH * FZ * 2);
    u16* bufA = (u16*)alloc((size_t)n * FH * 2);
    u16* bufB = (u16*)alloc((size_t)n * FH * 2);

    // 1) prep: zero deg/total + weight convert (Wt[N][K] fp16)
    prep<<<464, 256, 0, stream>>>(W1, W2, W3, w1h, w2h, w3h, deg, total);
    // 2) degree histogram + edge ranks
    deg_count<<<E / 256, 256, 0, stream>>>(dst, deg, erank, E);
    // 3) single-kernel scan + dis
    scan_fused<<<n / 256, 256, 0, stream>>>(deg, total, rowstart, dis);
    // 4) conv1 GEMM (fused LN, dis-fold) with head-fused no-atomic csr fill -> T1 (bufA)
    gemm_ln<<<n / 128, 512, 0, stream>>>(x, w1h, lnw, lnb, dis, bufA,
                                         src, dst, erank, rowstart, csrc, E);
    // 5) fused agg1 + conv2 GEMM: gather T1 -> h1 -> @W2 -> T2 (bufB)
    gather_gemm<FH, FH><<<n / 128, 512, 0, stream>>>(bufA, w2h, rowstart, deg, csrc, dis, b1, bufB);
    // 6) fused agg2 + conv3 GEMM: gather T2 -> h2 -> @W3 -> T3 (bufA)
    gather_gemm<FH, FZ><<<n / 128, 512, 0, stream>>>(bufB, w3h, rowstart, deg, csrc, dis, b2, bufA);
    // 7) conv3 aggregate -> out
    agg32h<<<n / 4, 256, 0, stream>>>(bufA, rowstart, deg, csrc, dis, b3, out);
}

// Round 17
// 145.118 us; speedup vs baseline: 1.3795x; 1.0637x over previous
//
#include <hip/hip_runtime.h>
#include <hip/hip_bf16.h>

#define FIN 256
#define FH 128
#define FZ 32

typedef unsigned short u16;
typedef unsigned int u32;
typedef __attribute__((ext_vector_type(4))) float f32x4;
typedef __attribute__((ext_vector_type(8))) _Float16 f16x8;
typedef __attribute__((ext_vector_type(4))) _Float16 f16x4;
typedef __attribute__((ext_vector_type(4))) unsigned int uint4v;

__device__ inline u16 f2h(float v) { return __builtin_bit_cast(u16, (_Float16)v); }

// ---------------- prep: zero deg/total + weight convert to fp16 Wt[N][K] ----------------
__global__ __launch_bounds__(256) void prep(const float* __restrict__ W1,
                                            const float* __restrict__ W2,
                                            const float* __restrict__ W3,
                                            u16* __restrict__ w1h, u16* __restrict__ w2h,
                                            u16* __restrict__ w3h, int* __restrict__ deg,
                                            int* __restrict__ total) {
    int b = blockIdx.x, t = threadIdx.x;
    if (b < 256) {
        deg[b * 256 + t] = 0;
        if (b == 0 && t == 0) *total = 0;
        return;
    }
    int i = (b - 256) * 256 + t;
    if (i < FIN * FH) {
        int k = i / FH, n = i % FH;
        w1h[n * FIN + k] = f2h(W1[i]);
    } else if (i < FIN * FH + FH * FH) {
        int j = i - FIN * FH;
        int k = j / FH, n = j % FH;
        w2h[n * FH + k] = f2h(W2[j]);
    } else {
        int j = i - (FIN * FH + FH * FH);
        int k = j / FZ, n = j % FZ;
        w3h[n * FH + k] = f2h(W3[j]);
    }
}

// ---------------- degree count + per-edge rank (atomic return value) ----------------
__global__ void deg_count(const int* __restrict__ dst, int* __restrict__ deg,
                          int* __restrict__ erank, int E) {
    int e = blockIdx.x * 256 + threadIdx.x;
    if (e < E) erank[e] = atomicAdd(&deg[dst[e]], 1);
}

// ---------------- single-kernel scan: block-local scan + atomic base ----------------
__global__ __launch_bounds__(256) void scan_fused(const int* __restrict__ deg,
                                                  int* __restrict__ total,
                                                  int* __restrict__ rowstart,
                                                  float* __restrict__ dis) {
    __shared__ int s[256];
    __shared__ int base;
    int t = threadIdx.x;
    int i = blockIdx.x * 256 + t;
    int v = deg[i];
    s[t] = v;
    __syncthreads();
    for (int o = 1; o < 256; o <<= 1) {
        int add = (t >= o) ? s[t - o] : 0;
        __syncthreads();
        s[t] += add;
        __syncthreads();
    }
    if (t == 255) base = atomicAdd(total, s[255]);
    __syncthreads();
    rowstart[i] = s[t] - v + base;
    dis[i] = rsqrtf((float)v + 1.0f);
}

// ---------------- conv1 GEMM: single-pass LN (raw-fp16 regs + fp32 stats), full W LDS, tail fill ----------------
__global__ __launch_bounds__(512) void gemm_ln(
    const float* __restrict__ Xf, const u16* __restrict__ Wg,
    const float* __restrict__ lnw, const float* __restrict__ lnb,
    const float* __restrict__ dis, u16* __restrict__ Y,
    const int* __restrict__ src, const int* __restrict__ dst,
    const int* __restrict__ erank, const int* __restrict__ rowstart,
    int* __restrict__ csrc, int E) {
    constexpr int K = FIN, N = FH;
    constexpr int BM = 128, NT = N / 16, NK = K / 32;

    __shared__ u16 Wl[N * K];

    const int t = threadIdx.x;
    const int row0 = blockIdx.x * BM;
    const int wave = t >> 6, l = t & 63;
    const int lm = l & 15, lq = l >> 4;
    const int row = row0 + wave * 16 + lm;

    // single pass over x: stats + immediate fp16 convert (32 VGPRs held)
    const float* xr = Xf + (long long)row * K;
    f16x8 a[NK];
    float s = 0.f, ss = 0.f;
#pragma unroll
    for (int kk = 0; kk < NK; ++kk) {
        f32x4 x0 = *(const f32x4*)(xr + kk * 32 + lq * 8);
        f32x4 x1 = *(const f32x4*)(xr + kk * 32 + lq * 8 + 4);
#pragma unroll
        for (int c = 0; c < 4; ++c) {
            s += x0[c] + x1[c];
            ss += x0[c] * x0[c] + x1[c] * x1[c];
            a[kk][c] = (_Float16)x0[c];
            a[kk][4 + c] = (_Float16)x1[c];
        }
    }
    s += __shfl_xor(s, 16);
    ss += __shfl_xor(ss, 16);
    s += __shfl_xor(s, 32);
    ss += __shfl_xor(ss, 32);
    float mu = s * (1.0f / K);
    float rs = rsqrtf(fmaxf(ss * (1.0f / K) - mu * mu, 0.f) + 1e-5f);

    // stage W (swizzled) while stats settle
    for (int i = t; i < N * K / 8; i += 512) {
        int nn = i / (K / 8), k8 = i % (K / 8);
        *(uint4v*)&Wl[nn * K + ((k8 ^ (nn & 7)) * 8)] = *(const uint4v*)&Wg[nn * K + k8 * 8];
    }

    // normalize in-register (lnw/lnb from L2 - 2KB shared across all blocks)
#pragma unroll
    for (int kk = 0; kk < NK; ++kk) {
        f32x4 w0 = *(const f32x4*)(lnw + kk * 32 + lq * 8);
        f32x4 w1 = *(const f32x4*)(lnw + kk * 32 + lq * 8 + 4);
        f32x4 c0 = *(const f32x4*)(lnb + kk * 32 + lq * 8);
        f32x4 c1 = *(const f32x4*)(lnb + kk * 32 + lq * 8 + 4);
#pragma unroll
        for (int c = 0; c < 4; ++c) {
            a[kk][c] = (_Float16)(((float)a[kk][c] - mu) * rs * w0[c] + c0[c]);
            a[kk][4 + c] = (_Float16)(((float)a[kk][4 + c] - mu) * rs * w1[c] + c1[c]);
        }
    }
    __syncthreads();

    f32x4 acc[NT];
#pragma unroll
    for (int i = 0; i < NT; ++i) acc[i] = (f32x4){0.f, 0.f, 0.f, 0.f};
#pragma unroll
    for (int kk = 0; kk < NK; ++kk) {
#pragma unroll
        for (int nt = 0; nt < NT; ++nt) {
            int nn = nt * 16 + lm;
            f16x8 wv = *(const f16x8*)&Wl[nn * K + (((kk * 4 + lq) ^ (nn & 7)) * 8)];
            acc[nt] = __builtin_amdgcn_mfma_f32_16x16x32_f16(wv, a[kk], acc[nt], 0, 0, 0);
        }
    }

    const float di = dis[row];
    u16* yr = Y + (long long)row * N;
#pragma unroll
    for (int nt = 0; nt < NT; ++nt) {
        f16x4 v;
#pragma unroll
        for (int r = 0; r < 4; ++r) v[r] = (_Float16)(acc[nt][r] * di);
        *(f16x4*)&yr[nt * 16 + lq * 4] = v;
    }

    // tail-fused no-atomic csr fill (retires with the wave)
    {
        int epb = E / gridDim.x;
        int base = blockIdx.x * epb;
        for (int j = t; j < epb; j += 512) {
            int e = base + j;
            int d = dst[e];
            csrc[rowstart[d] + erank[e]] = src[e];
        }
    }
}

// ---------------- gather_gemm: fused CSR-gather aggregation + GEMM ----------------
// h[row] = relu(dis[row] * (sum_{s in N(row)} T[s] + T[row]) + b)   (fp32, in-register)
// Y[row] = dis[row] * (h[row] @ W)                                  (fp16 out)
template <int K, int N>
__global__ __launch_bounds__(512) void gather_gemm(
    const u16* __restrict__ T, const u16* __restrict__ Wg,
    const int* __restrict__ rowstart, const int* __restrict__ degv,
    const int* __restrict__ csrc, const float* __restrict__ dis,
    const float* __restrict__ bias, u16* __restrict__ Y) {
    constexpr int BM = 128, NT = N / 16, NK = K / 32;

    __shared__ u16 Wl[N * K];
    __shared__ float bl[K];

    const int t = threadIdx.x;
    const int row0 = blockIdx.x * BM;
    const int wave = t >> 6, l = t & 63;
    const int lm = l & 15, lq = l >> 4;
    const int row = row0 + wave * 16 + lm;

    // stage W (swizzled) + bias
    for (int i = t; i < N * K / 8; i += 512) {
        int nn = i / (K / 8), k8 = i % (K / 8);
        *(uint4v*)&Wl[nn * K + ((k8 ^ (nn & 7)) * 8)] = *(const uint4v*)&Wg[nn * K + k8 * 8];
    }
    if (t < K / 4) *(f32x4*)&bl[t * 4] = *(const f32x4*)&bias[t * 4];

    // gather this row's aggregate into fp32 regs (4 lanes per row, 16B slices)
    const float di = dis[row];
    const int rs = rowstart[row], dg = degv[row];
    float g[NK][8];
    {
        const u16* tr = T + (long long)row * K;
#pragma unroll
        for (int kk = 0; kk < NK; ++kk) {
            f16x8 v = *(const f16x8*)&tr[kk * 32 + lq * 8];
#pragma unroll
            for (int j = 0; j < 8; ++j) g[kk][j] = (float)v[j];
        }
    }
    int e = rs, e1 = rs + dg;
    for (; e + 1 < e1; e += 2) {
        int s0 = csrc[e], s1 = csrc[e + 1];
        const u16* t0 = T + (long long)s0 * K;
        const u16* t1 = T + (long long)s1 * K;
#pragma unroll
        for (int kk = 0; kk < NK; ++kk) {
            f16x8 v0 = *(const f16x8*)&t0[kk * 32 + lq * 8];
            f16x8 v1 = *(const f16x8*)&t1[kk * 32 + lq * 8];
#pragma unroll
            for (int j = 0; j < 8; ++j) g[kk][j] += (float)v0[j] + (float)v1[j];
        }
    }
    if (e < e1) {
        const u16* t0 = T + (long long)csrc[e] * K;
#pragma unroll
        for (int kk = 0; kk < NK; ++kk) {
            f16x8 v0 = *(const f16x8*)&t0[kk * 32 + lq * 8];
#pragma unroll
            for (int j = 0; j < 8; ++j) g[kk][j] += (float)v0[j];
        }
    }
    __syncthreads();

    // h = relu(g*di + b) -> fp16 fragments
    f16x8 a[NK];
#pragma unroll
    for (int kk = 0; kk < NK; ++kk) {
#pragma unroll
        for (int j = 0; j < 8; ++j) {
            float h = fmaxf(g[kk][j] * di + bl[kk * 32 + lq * 8 + j], 0.f);
            a[kk][j] = (_Float16)h;
        }
    }

    f32x4 acc[NT];
#pragma unroll
    for (int i = 0; i < NT; ++i) acc[i] = (f32x4){0.f, 0.f, 0.f, 0.f};
#pragma unroll
    for (int kk = 0; kk < NK; ++kk) {
#pragma unroll
        for (int nt = 0; nt < NT; ++nt) {
            int nn = nt * 16 + lm;
            f16x8 wv = *(const f16x8*)&Wl[nn * K + (((kk * 4 + lq) ^ (nn & 7)) * 8)];
            acc[nt] = __builtin_amdgcn_mfma_f32_16x16x32_f16(wv, a[kk], acc[nt], 0, 0, 0);
        }
    }

    u16* yr = Y + (long long)row * N;
#pragma unroll
    for (int nt = 0; nt < NT; ++nt) {
        f16x4 v;
#pragma unroll
        for (int r = 0; r < 4; ++r) v[r] = (_Float16)(acc[nt][r] * di);
        *(f16x4*)&yr[nt * 16 + lq * 4] = v;
    }
}

// ---------------- F=32 gather -> fp32 out ----------------
__global__ __launch_bounds__(256) void agg32h(
    const u16* __restrict__ T, const int* __restrict__ rowstart, const int* __restrict__ degv,
    const int* __restrict__ csrc, const float* __restrict__ dis, const float* __restrict__ bias,
    float* __restrict__ OUT) {
    int node = blockIdx.x * 4 + (threadIdx.x >> 6);
    int l = threadIdx.x & 63;
    int h = l >> 3, c = l & 7;  // 8 edge slots x 8 lanes x 4 feats
    float di = dis[node];
    f32x4 acc = (f32x4){0.f, 0.f, 0.f, 0.f};
    if (h == 0) {
        f16x4 s = *(const f16x4*)&T[(long long)node * 32 + c * 4];
#pragma unroll
        for (int i = 0; i < 4; ++i) acc[i] = (float)s[i];
    }
    int e0 = rowstart[node];
    int e1 = e0 + degv[node];
    int e = e0 + h;
    for (; e + 8 < e1; e += 16) {
        int s0 = csrc[e], s1 = csrc[e + 8];
        f16x4 u0 = *(const f16x4*)&T[(long long)s0 * 32 + c * 4];
        f16x4 u1 = *(const f16x4*)&T[(long long)s1 * 32 + c * 4];
#pragma unroll
        for (int i = 0; i < 4; ++i) acc[i] += (float)u0[i] + (float)u1[i];
    }
    if (e < e1) {
        int s0 = csrc[e];
        f16x4 u0 = *(const f16x4*)&T[(long long)s0 * 32 + c * 4];
#pragma unroll
        for (int i = 0; i < 4; ++i) acc[i] += (float)u0[i];
    }
#pragma unroll
    for (int m = 8; m <= 32; m <<= 1) {
#pragma unroll
        for (int i = 0; i < 4; ++i) acc[i] += __shfl_xor(acc[i], m);
    }
    if (h == 0) {
        f32x4 b0 = *(const f32x4*)(bias + c * 4);
        f32x4 r;
#pragma unroll
        for (int i = 0; i < 4; ++i) r[i] = acc[i] * di + b0[i];
        *(f32x4*)(OUT + (long long)node * 32 + c * 4) = r;
    }
}

extern "C" void kernel_launch(void* const* d_in, const int* in_sizes, int n_in,
                              void* d_out, int out_size, void* d_ws, size_t ws_size,
                              hipStream_t stream) {
    const float* x = (const float*)d_in[0];
    const int* ei = (const int*)d_in[1];
    const float* lnw = (const float*)d_in[2];
    const float* lnb = (const float*)d_in[3];
    const float* W1 = (const float*)d_in[4];
    const float* b1 = (const float*)d_in[5];
    const float* W2 = (const float*)d_in[6];
    const float* b2 = (const float*)d_in[7];
    const float* W3 = (const float*)d_in[8];
    const float* b3 = (const float*)d_in[9];
    float* out = (float*)d_out;

    const int n = in_sizes[0] / FIN;  // 65536
    const int E = in_sizes[1] / 2;    // 524288
    const int* src = ei;
    const int* dst = ei + E;

    char* w = (char*)d_ws;
    auto alloc = [&](size_t bytes) {
        char* p = w;
        w += (bytes + 255) & ~(size_t)255;
        return p;
    };
    int* deg = (int*)alloc((size_t)n * 4);
    int* rowstart = (int*)alloc((size_t)n * 4);
    int* erank = (int*)alloc((size_t)E * 4);
    int* total = (int*)alloc(256);
    float* dis = (float*)alloc((size_t)n * 4);
    int* csrc = (int*)alloc((size_t)E * 4);
    u16* w1h = (u16*)alloc(FIN * FH * 2);
    u16* w2h = (u16*)alloc(FH * FH * 2);
    u16* w3h = (u16*)alloc(FH * FZ * 2);
    u16* bufA = (u16*)alloc((size_t)n * FH * 2);
    u16* bufB = (u16*)alloc((size_t)n * FH * 2);

    // 1) prep: zero deg/total + weight convert (Wt[N][K] fp16)
    prep<<<464, 256, 0, stream>>>(W1, W2, W3, w1h, w2h, w3h, deg, total);
    // 2) degree histogram + edge ranks
    deg_count<<<E / 256, 256, 0, stream>>>(dst, deg, erank, E);
    // 3) single-kernel scan + dis
    scan_fused<<<n / 256, 256, 0, stream>>>(deg, total, rowstart, dis);
    // 4) conv1 GEMM (single-pass fused LN, dis-fold) with tail-fused no-atomic csr fill -> T1 (bufA)
    gemm_ln<<<n / 128, 512, 0, stream>>>(x, w1h, lnw, lnb, dis, bufA,
                                         src, dst, erank, rowstart, csrc, E);
    // 5) fused agg1 + conv2 GEMM: gather T1 -> h1 -> @W2 -> T2 (bufB)
    gather_gemm<FH, FH><<<n / 128, 512, 0, stream>>>(bufA, w2h, rowstart, deg, csrc, dis, b1, bufB);
    // 6) fused agg2 + conv3 GEMM: gather T2 -> h2 -> @W3 -> T3 (bufA)
    gather_gemm<FH, FZ><<<n / 128, 512, 0, stream>>>(bufB, w3h, rowstart, deg, csrc, dis, b2, bufA);
    // 7) conv3 aggregate -> out
    agg32h<<<n / 4, 256, 0, stream>>>(bufA, rowstart, deg, csrc, dis, b3, out);
}